// Round 7
// baseline (214.321 us; speedup 1.0000x reference)
//
#include <hip/hip_runtime.h>
#include <hip/hip_bf16.h>

#define BB 16
#define NN 4096
#define DD 64
#define NM1 4095

typedef __bf16 bf16x8 __attribute__((ext_vector_type(8)));
typedef float f32x4 __attribute__((ext_vector_type(4)));

typedef __attribute__((address_space(1))) const void gas_void;
typedef __attribute__((address_space(3))) void las_void;

// ws layout:
//   [0]        float mx[4096]          (16 KB)  -- zeroed via memsetAsync
//   [16384]    float ss[4096]          (16 KB)  -- zeroed via memsetAsync
//   [32768]    __bf16 XT[16][64][4096] ( 8 MiB)
//   [+8 MiB]   __bf16 A16[4096][4096]  (32 MiB)

// ---------------------------------------------------------------------------
// Kernel 1: flat scatter build (f32 + bf16 copies), l1/l2 via atomics.
// ---------------------------------------------------------------------------
__global__ __launch_bounds__(256) void build_kernel(
    const float* __restrict__ inc, float* __restrict__ out_inc,
    __bf16* __restrict__ A16, float* __restrict__ mxa, float* __restrict__ ssa)
{
    int t = threadIdx.x;
    int base = blockIdx.x << 12;                 // 4096 elems per block
    int rA = (int)((unsigned)base / NM1);        // block spans rows {rA, rA+1}
    float pm0 = 0.f, ps0 = 0.f, pm1 = 0.f, ps1 = 0.f;
    #pragma unroll
    for (int j = 0; j < 16; ++j) {
        int f = base + j * 256 + t;
        int i = (int)((unsigned)f / NM1);
        int c = f - i * NM1;
        float x = inc[f];
        float w = x > 0.01f ? x : 0.f;
        int dst = f + i + (c >= i);              // i*4096 + c + (c>=i)
        out_inc[dst] = w;
        A16[dst] = (__bf16)w;
        if (i == rA) { pm0 = fmaxf(pm0, w); ps0 += w * w; }
        else         { pm1 = fmaxf(pm1, w); ps1 += w * w; }
    }
    #pragma unroll
    for (int off = 32; off; off >>= 1) {
        pm0 = fmaxf(pm0, __shfl_down(pm0, off));
        ps0 += __shfl_down(ps0, off);
        pm1 = fmaxf(pm1, __shfl_down(pm1, off));
        ps1 += __shfl_down(ps1, off);
    }
    __shared__ float sm0[4], sq0[4], sm1[4], sq1[4];
    int wid = t >> 6;
    if ((t & 63) == 0) { sm0[wid] = pm0; sq0[wid] = ps0; sm1[wid] = pm1; sq1[wid] = ps1; }
    __syncthreads();
    if (t == 0) {
        float m0v = fmaxf(fmaxf(sm0[0], sm0[1]), fmaxf(sm0[2], sm0[3]));
        float s0v = sq0[0] + sq0[1] + sq0[2] + sq0[3];
        float m1v = fmaxf(fmaxf(sm1[0], sm1[1]), fmaxf(sm1[2], sm1[3]));
        float s1v = sq1[0] + sq1[1] + sq1[2] + sq1[3];
        atomicMax((unsigned*)(mxa + rA), __float_as_uint(m0v));
        atomicAdd(ssa + rA, s0v);
        int rB = rA + 1;
        if (rB < NN) {
            atomicMax((unsigned*)(mxa + rB), __float_as_uint(m1v));
            atomicAdd(ssa + rB, s1v);
        }
    }
}

// ---------------------------------------------------------------------------
// Kernel 2: XT[b][d][n] = (bf16)X[b][n][d] + diagonal writes
// ---------------------------------------------------------------------------
__global__ __launch_bounds__(256) void xt_kernel(
    const float* __restrict__ X, __bf16* __restrict__ XT,
    float* __restrict__ out_inc, __bf16* __restrict__ A16)
{
    __shared__ __bf16 tile[64 * 72];
    int t = threadIdx.x;
    int ntile = blockIdx.x, b = blockIdx.y;
    int n = t >> 2, q = t & 3;
    const float* src = X + ((size_t)b * NN + ntile * 64 + n) * DD + q * 16;
    #pragma unroll
    for (int v = 0; v < 4; ++v) {
        f32x4 u = *(const f32x4*)(src + v * 4);
        #pragma unroll
        for (int j = 0; j < 4; ++j) {
            int d = q * 16 + v * 4 + j;
            tile[d * 72 + n] = (__bf16)u[j];
        }
    }
    __syncthreads();
    int d = t >> 2;
    __bf16* dst = XT + ((size_t)b * DD + d) * NN + ntile * 64 + q * 16;
    *(bf16x8*)dst       = *(bf16x8*)&tile[d * 72 + q * 16];
    *(bf16x8*)(dst + 8) = *(bf16x8*)&tile[d * 72 + q * 16 + 8];
    if (b == 0 && t < 64) {
        int r = ntile * 64 + t;
        out_inc[(size_t)r * NN + r] = 1.0f;
        A16[(size_t)r * NN + r] = (__bf16)1.0f;
    }
}

// ---------------------------------------------------------------------------
// Kernel 3: barrier-free per-wave-pipelined GEMM + fused loss.
//   Block 64m x 64n (one batch), grid (64,16) = 1024 blocks = 4/CU.
//   4 waves split K: wave w does k-tiles w, w+4, ..., w+124 (BK=32, 32 iters),
//   each with a private 8 KB LDS buffer; NO __syncthreads in the K-loop.
//   Slot map slot(row,oct) = row*4 + (oct ^ ((row>>1)&3)): frag ds_read_b128
//   2-way bank (free), staging fully coalesced.
//   End: 3-round LDS exchange reduces the 4 partial accs (wave w owns rows
//   w*16..w*16+15); xp folded as D = X.(-(r+I)) + acc (MFMA, C=acc).
//   All acc[] indices are compile-time (wave-uniform predicated loops).
// ---------------------------------------------------------------------------
__global__ __launch_bounds__(256, 4) void gemm_loss_kernel(
    const __bf16* __restrict__ A16, const __bf16* __restrict__ XT,
    const float* __restrict__ X, const float* __restrict__ rproj,
    const float* __restrict__ mxa, const float* __restrict__ ssa,
    float* __restrict__ loss)
{
    __shared__ __bf16 lds[4 * 4096];             // 32 KB: 8 KB per wave

    int t = threadIdx.x;
    int wave = t >> 6, lane = t & 63;
    int quad = lane >> 4, ln = lane & 15;
    int m0 = blockIdx.x * 64;
    int b  = blockIdx.y;

    __bf16* Abuf = lds + wave * 4096;            // 4 KB (2048 elems)
    __bf16* Xbuf = Abuf + 2048;                  // 4 KB

    const __bf16* Abase = A16 + (size_t)m0 * NN;
    const __bf16* Xbase = XT + (size_t)b * DD * NN;

    f32x4 acc[4][4];
    f32x4 zero = {0.f, 0.f, 0.f, 0.f};
    #pragma unroll
    for (int mt = 0; mt < 4; ++mt)
        #pragma unroll
        for (int nt = 0; nt < 4; ++nt) acc[mt][nt] = zero;

    // staging lane->slot geometry (constant per thread)
    int srow_lo = lane >> 2;                     // 0..15 within 16-row group
    int soct = (lane & 3) ^ ((srow_lo >> 1) & 3);

    // prologue: stage tile i=0 (k0 = wave*32)
    {
        int k0 = wave * 32;
        #pragma unroll
        for (int p = 0; p < 4; ++p) {
            int srow = p * 16 + srow_lo;
            __builtin_amdgcn_global_load_lds(
                (gas_void*)(Abase + (size_t)srow * NN + k0 + soct * 8),
                (las_void*)(Abuf + p * 512), 16, 0, 0);
            __builtin_amdgcn_global_load_lds(
                (gas_void*)(Xbase + (size_t)srow * NN + k0 + soct * 8),
                (las_void*)(Xbuf + p * 512), 16, 0, 0);
        }
    }

    for (int i = 0; i < 32; ++i) {               // 4 waves x 32 x BK=32 = K=4096
        __builtin_amdgcn_s_waitcnt(0x0F70);      // vmcnt(0): this wave's stage done
        bf16x8 af[4], bfr[4];
        #pragma unroll
        for (int mt = 0; mt < 4; ++mt) {
            int r = mt * 16 + ln;
            int slot = r * 4 + (quad ^ ((ln >> 1) & 3));
            af[mt] = *(const bf16x8*)&Abuf[slot * 8];
        }
        #pragma unroll
        for (int nt = 0; nt < 4; ++nt) {
            int n = nt * 16 + ln;
            int slot = n * 4 + (quad ^ ((ln >> 1) & 3));
            bfr[nt] = *(const bf16x8*)&Xbuf[slot * 8];
        }
        __builtin_amdgcn_s_waitcnt(0xC07F);      // lgkmcnt(0): frags in VGPRs
        __builtin_amdgcn_sched_barrier(0);
        if (i < 31) {                            // stage next tile, same buffer
            int k0 = (wave + 4 * (i + 1)) * 32;
            #pragma unroll
            for (int p = 0; p < 4; ++p) {
                int srow = p * 16 + srow_lo;
                __builtin_amdgcn_global_load_lds(
                    (gas_void*)(Abase + (size_t)srow * NN + k0 + soct * 8),
                    (las_void*)(Abuf + p * 512), 16, 0, 0);
                __builtin_amdgcn_global_load_lds(
                    (gas_void*)(Xbase + (size_t)srow * NN + k0 + soct * 8),
                    (las_void*)(Xbuf + p * 512), 16, 0, 0);
            }
        }
        __builtin_amdgcn_sched_barrier(0);
        #pragma unroll
        for (int mt = 0; mt < 4; ++mt)
            #pragma unroll
            for (int nt = 0; nt < 4; ++nt)
                acc[mt][nt] = __builtin_amdgcn_mfma_f32_16x16x32_bf16(
                    af[mt], bfr[nt], acc[mt][nt], 0, 0, 0);
    }

    // ---- 3-round reduction: wave w ends owning full-K acc for rows w*16.. ----
    // All acc indices compile-time; conditions wave-uniform.
    float* red = (float*)lds;                    // 4 regions x 4 KB
    #pragma unroll
    for (int r = 1; r < 4; ++r) {
        __syncthreads();
        #pragma unroll
        for (int p = 0; p < 4; ++p) {
            if (((p - wave + 4) & 3) == r) {     // wave sends frag p this round
                #pragma unroll
                for (int nt = 0; nt < 4; ++nt)
                    *(f32x4*)&red[p * 1024 + nt * 256 + lane * 4] = acc[p][nt];
            }
        }
        __syncthreads();
        #pragma unroll
        for (int p = 0; p < 4; ++p) {
            if (p == wave) {                     // wave receives its own frag
                #pragma unroll
                for (int nt = 0; nt < 4; ++nt)
                    acc[p][nt] += *(const f32x4*)&red[p * 1024 + nt * 256 + lane * 4];
            }
        }
    }

    f32x4 dacc[4];
    #pragma unroll
    for (int p = 0; p < 4; ++p) {
        if (p == wave) {
            #pragma unroll
            for (int nt = 0; nt < 4; ++nt) dacc[nt] = acc[p][nt];
        }
    }

    // ---- phase 2: D = Xrows @ (-(r+I)) + acc  (rows wave*16+ln) ----
    #pragma unroll
    for (int kk = 0; kk < DD; kk += 32) {
        const float* xs = X + ((size_t)b * NN + m0 + wave * 16 + ln) * DD + kk + quad * 8;
        f32x4 u0 = *(const f32x4*)xs;
        f32x4 u1 = *(const f32x4*)(xs + 4);
        bf16x8 afp;
        #pragma unroll
        for (int j = 0; j < 4; ++j) { afp[j] = (__bf16)u0[j]; afp[j + 4] = (__bf16)u1[j]; }
        #pragma unroll
        for (int nt = 0; nt < 4; ++nt) {
            bf16x8 bn;
            #pragma unroll
            for (int j = 0; j < 8; ++j) {
                int e = kk + quad * 8 + j;       // k index
                int d = nt * 16 + ln;            // output col
                float val = rproj[(size_t)e * DD + d] + (e == d ? 1.0f : 0.0f);
                bn[j] = (__bf16)(-val);
            }
            dacc[nt] = __builtin_amdgcn_mfma_f32_16x16x32_bf16(
                afp, bn, dacc[nt], 0, 0, 0);
        }
    }

    // ---- loss: row = m0 + wave*16 + quad*4 + rg ----
    #pragma unroll
    for (int rg = 0; rg < 4; ++rg) {
        float s = 0.f;
        #pragma unroll
        for (int nt = 0; nt < 4; ++nt) {
            float df = dacc[nt][rg];
            s += df * df;
        }
        s += __shfl_xor(s, 1);
        s += __shfl_xor(s, 2);
        s += __shfl_xor(s, 4);
        s += __shfl_xor(s, 8);
        if (ln == 0) {
            int row = m0 + wave * 16 + quad * 4 + rg;
            loss[(size_t)b * NN + row] =
                0.2f * sqrtf(s) + mxa[row] + 0.001f * sqrtf(ssa[row]);
        }
    }
}

extern "C" void kernel_launch(void* const* d_in, const int* in_sizes, int n_in,
                              void* d_out, int out_size, void* d_ws, size_t ws_size,
                              hipStream_t stream) {
    const float* X   = (const float*)d_in[0];   // [B][N][D] f32
    const float* r   = (const float*)d_in[1];   // [D][D] f32
    const float* inc = (const float*)d_in[2];   // [N][N-1] f32
    float* out      = (float*)d_out;
    float* out_loss = out;                       // [B][N]
    float* out_inc  = out + (size_t)BB * NN;     // [N][N]

    char* ws = (char*)d_ws;
    float*  mxa = (float*)ws;
    float*  ssa = (float*)(ws + 16384);
    __bf16* XT  = (__bf16*)(ws + 32768);
    __bf16* A16 = (__bf16*)(ws + 32768 + (size_t)8 * 1024 * 1024);

    hipMemsetAsync(mxa, 0, 32768, stream);

    hipLaunchKernelGGL(build_kernel, dim3(NM1), dim3(256), 0, stream,
                       inc, out_inc, A16, mxa, ssa);
    hipLaunchKernelGGL(xt_kernel, dim3(NN / 64, BB), dim3(256), 0, stream,
                       X, XT, out_inc, A16);
    hipLaunchKernelGGL(gemm_loss_kernel, dim3(NN / 64, BB), dim3(256), 0, stream,
                       A16, XT, X, r, mxa, ssa, out_loss);
}